// Round 1
// baseline (1464.482 us; speedup 1.0000x reference)
//
#include <hip/hip_runtime.h>

#define NPTS 8192
#define KNNK 16
#define NSLOT 17          // keep 17, fp64-refine drops the worst -> robust 16-set
#define LEAKY 0.1f
#define TP 4              // points per block in feature kernel

// ---------------------------------------------------------------------------
// Kernel 1: brute-force exact KNN (top-16 of 8192) for all 4 (dir,b) combos.
// One thread per query. Candidates staged in LDS (96 KB), broadcast reads.
// Per-thread sorted-descending insertion list of 17 (dist,idx) in registers.
// ---------------------------------------------------------------------------
__global__ __launch_bounds__(256) void knn_kernel(
    const float* __restrict__ pc1, const float* __restrict__ pc2,
    int* __restrict__ knn_out)
{
    __shared__ float cand[NPTS * 3];

    const int q   = blockIdx.x * 256 + threadIdx.x;   // 0..32767
    const int dir = q >> 14;                          // 0: query=pc1,cand=pc2
    const int b   = (q >> 13) & 1;
    const int n   = q & (NPTS - 1);

    const float* __restrict__ pq = dir ? pc2 : pc1;
    const float* __restrict__ pc = dir ? pc1 : pc2;

    // stage candidate cloud for this (dir,b) -- whole block shares it
    const float* src = pc + (size_t)b * NPTS * 3;
    for (int i = threadIdx.x; i < NPTS * 3; i += 256) cand[i] = src[i];
    __syncthreads();

    const float* qp = pq + ((size_t)b * NPTS + n) * 3;
    const float qx = qp[0], qy = qp[1], qz = qp[2];

    float dist[NSLOT];   // sorted descending: dist[0] = worst kept
    int   ind[NSLOT];
#pragma unroll
    for (int i = 0; i < NSLOT; ++i) { dist[i] = 3.0e38f; ind[i] = 0; }

    for (int k = 0; k < NPTS; ++k) {
        const float dx = cand[3 * k]     - qx;
        const float dy = cand[3 * k + 1] - qy;
        const float dz = cand[3 * k + 2] - qz;
        const float d = fmaf(dx, dx, fmaf(dy, dy, dz * dz));
        if (d < dist[0]) {
            // branchless sorted shift-insert (drop current max at slot 0)
            bool cprev = true;
#pragma unroll
            for (int i = 0; i < NSLOT - 1; ++i) {
                const bool ci = d < dist[i + 1];
                const float nv = ci ? dist[i + 1] : (cprev ? d : dist[i]);
                const int   ni = ci ? ind[i + 1]  : (cprev ? k : ind[i]);
                dist[i] = nv; ind[i] = ni;
                cprev = ci;
            }
            if (cprev) { dist[NSLOT - 1] = d; ind[NSLOT - 1] = k; }
        }
    }

    // fp64 refine: among the 17 survivors, drop the one with largest exact
    // distance. Makes the 16-set immune to fp32 rounding at the boundary.
    double dd[NSLOT];
#pragma unroll
    for (int i = 0; i < NSLOT; ++i) {
        const int id = ind[i];
        const double dx = (double)cand[3 * id]     - (double)qx;
        const double dy = (double)cand[3 * id + 1] - (double)qy;
        const double dz = (double)cand[3 * id + 2] - (double)qz;
        dd[i] = dx * dx + dy * dy + dz * dz;
    }
    int worst = 0; double wd = dd[0];
#pragma unroll
    for (int i = 1; i < NSLOT; ++i) { if (dd[i] > wd) { wd = dd[i]; worst = i; } }

    int* outp = knn_out + (size_t)q * KNNK;
    int slot = 0;
#pragma unroll
    for (int i = 0; i < NSLOT; ++i) {
        if (i != worst) outp[slot++] = ind[i];
    }
}

// ---------------------------------------------------------------------------
// Kernel 2: fused gather + pos-MLP + 2x (64x64 leaky MLP) + max-pool + 64->128
// Block = 256 threads = 4 point-groups x 64 channel-threads. LDS tiles with
// +4 row padding (stride 68) to keep bank conflicts <= 2-way.
// ---------------------------------------------------------------------------
__device__ __forceinline__ void mlp_layer(
    const float (* __restrict__ in)[68], float (* __restrict__ outp)[68],
    const float (* __restrict__ w)[68], const float* __restrict__ bias, int c)
{
    // thread c: c0 = c&15 -> output channels {c0, c0+16, c0+32, c0+48}
    //           kb = (c>>4)*4 -> neighbors {kb..kb+3}
    const int c0 = c & 15;
    const int kb = (c >> 4) * 4;
    float acc[4][4];
#pragma unroll
    for (int kk = 0; kk < 4; ++kk)
#pragma unroll
        for (int j = 0; j < 4; ++j) acc[kk][j] = 0.f;

#pragma unroll
    for (int cc = 0; cc < 64; cc += 4) {
        float4 wv[4];
#pragma unroll
        for (int j = 0; j < 4; ++j)
            wv[j] = *(const float4*)&w[c0 + 16 * j][cc];
#pragma unroll
        for (int kk = 0; kk < 4; ++kk) {
            const float4 av = *(const float4*)&in[kb + kk][cc];
#pragma unroll
            for (int j = 0; j < 4; ++j) {
                acc[kk][j] = fmaf(av.x, wv[j].x, acc[kk][j]);
                acc[kk][j] = fmaf(av.y, wv[j].y, acc[kk][j]);
                acc[kk][j] = fmaf(av.z, wv[j].z, acc[kk][j]);
                acc[kk][j] = fmaf(av.w, wv[j].w, acc[kk][j]);
            }
        }
    }
#pragma unroll
    for (int kk = 0; kk < 4; ++kk)
#pragma unroll
        for (int j = 0; j < 4; ++j) {
            float v = acc[kk][j] + bias[c0 + 16 * j];
            v = v >= 0.f ? v : LEAKY * v;
            outp[kb + kk][c0 + 16 * j] = v;
        }
}

__global__ __launch_bounds__(256) void feat_kernel(
    const float* __restrict__ pc1, const float* __restrict__ pc2,
    const float* __restrict__ feat1, const float* __restrict__ feat2,
    const float* __restrict__ pos_w, const float* __restrict__ pos_b,
    const float* __restrict__ w0, const float* __restrict__ b0,
    const float* __restrict__ w1, const float* __restrict__ b1,
    const float* __restrict__ t1w, const float* __restrict__ t1b,
    const float* __restrict__ t2w, const float* __restrict__ t2b,
    const int* __restrict__ knn, float* __restrict__ out)
{
    __shared__ __align__(16) float sw0[64][68];
    __shared__ __align__(16) float sw1[64][68];
    __shared__ __align__(16) float tA[TP][16][68];
    __shared__ __align__(16) float tB[TP][16][68];
    __shared__ float sposw[3][64];
    __shared__ float sposb[64], sb0[64], sb1[64];
    __shared__ int   snidx[TP][16];
    __shared__ float sdir[TP][16][3];
    __shared__ __align__(16) float smax[TP][68];

    const int t = threadIdx.x;
    for (int i = t; i < 4096; i += 256) {
        sw0[i >> 6][i & 63] = w0[i];
        sw1[i >> 6][i & 63] = w1[i];
    }
    if (t < 64) {
        sposb[t] = pos_b[t]; sb0[t] = b0[t]; sb1[t] = b1[t];
        sposw[0][t] = pos_w[t * 3 + 0];
        sposw[1][t] = pos_w[t * 3 + 1];
        sposw[2][t] = pos_w[t * 3 + 2];
    }

    const int g = t >> 6, c = t & 63;
    const int p = blockIdx.x * TP + g;               // 0..32767
    const int dir = p >> 14, b = (p >> 13) & 1, n = p & (NPTS - 1);

    const float* pq = dir ? pc2 : pc1;
    const float* pc = dir ? pc1 : pc2;
    const float* fq = dir ? feat2 : feat1;
    const float* fc = dir ? feat1 : feat2;
    const float* tw = dir ? t2w : t1w;
    const float* tb = dir ? t2b : t1b;

    if (c < 16) {
        const int id = knn[(size_t)p * KNNK + c];
        snidx[g][c] = id;
        const float* qp  = pq + ((size_t)b * NPTS + n) * 3;
        const float* nbp = pc + ((size_t)b * NPTS + id) * 3;
        sdir[g][c][0] = nbp[0] - qp[0];
        sdir[g][c][1] = nbp[1] - qp[1];
        sdir[g][c][2] = nbp[2] - qp[2];
    }
    __syncthreads();

    // initial layer: leaky(g2 + p1 + pos_feat)
    {
        const float fqc = fq[((size_t)b * NPTS + n) * 64 + c];
        const float base = sposb[c] + fqc;
        const float pw0 = sposw[0][c], pw1 = sposw[1][c], pw2 = sposw[2][c];
#pragma unroll
        for (int k = 0; k < 16; ++k) {
            const int id = snidx[g][k];
            const float gf = fc[((size_t)b * NPTS + id) * 64 + c];
            float v = gf + base;
            v = fmaf(sdir[g][k][0], pw0, v);
            v = fmaf(sdir[g][k][1], pw1, v);
            v = fmaf(sdir[g][k][2], pw2, v);
            v = v >= 0.f ? v : LEAKY * v;
            tA[g][k][c] = v;
        }
    }
    __syncthreads();

    mlp_layer(tA[g], tB[g], sw0, sb0, c);
    __syncthreads();
    mlp_layer(tB[g], tA[g], sw1, sb1, c);
    __syncthreads();

    // max-pool over 16 neighbors
    {
        float m = tA[g][0][c];
#pragma unroll
        for (int k = 1; k < 16; ++k) m = fmaxf(m, tA[g][k][c]);
        smax[g][c] = m;
    }
    __syncthreads();

    // final 64 -> 128 linear (no activation); thread c -> outputs c, c+64
    {
        float acc0 = tb[c];
        float acc1 = tb[c + 64];
#pragma unroll
        for (int cc = 0; cc < 64; cc += 4) {
            const float4 mv = *(const float4*)&smax[g][cc];
            const float4 wa = *(const float4*)&tw[(size_t)c * 64 + cc];
            const float4 wb = *(const float4*)&tw[(size_t)(c + 64) * 64 + cc];
            acc0 = fmaf(mv.x, wa.x, acc0); acc0 = fmaf(mv.y, wa.y, acc0);
            acc0 = fmaf(mv.z, wa.z, acc0); acc0 = fmaf(mv.w, wa.w, acc0);
            acc1 = fmaf(mv.x, wb.x, acc1); acc1 = fmaf(mv.y, wb.y, acc1);
            acc1 = fmaf(mv.z, wb.z, acc1); acc1 = fmaf(mv.w, wb.w, acc1);
        }
        float* op = out + (size_t)dir * (2 * NPTS * 128)
                        + ((size_t)b * NPTS + n) * 128;
        op[c]      = acc0;
        op[c + 64] = acc1;
    }
}

// ---------------------------------------------------------------------------
extern "C" void kernel_launch(void* const* d_in, const int* in_sizes, int n_in,
                              void* d_out, int out_size, void* d_ws, size_t ws_size,
                              hipStream_t stream)
{
    const float* pc1   = (const float*)d_in[0];
    const float* pc2   = (const float*)d_in[1];
    const float* feat1 = (const float*)d_in[2];
    const float* feat2 = (const float*)d_in[3];
    const float* pos_w = (const float*)d_in[4];
    const float* pos_b = (const float*)d_in[5];
    const float* w0    = (const float*)d_in[6];
    const float* b0    = (const float*)d_in[7];
    const float* w1    = (const float*)d_in[8];
    const float* b1    = (const float*)d_in[9];
    const float* t1w   = (const float*)d_in[10];
    const float* t1b   = (const float*)d_in[11];
    const float* t2w   = (const float*)d_in[12];
    const float* t2b   = (const float*)d_in[13];

    int*   knn = (int*)d_ws;          // 32768 * 16 ints = 2 MB scratch
    float* out = (float*)d_out;

    hipLaunchKernelGGL(knn_kernel, dim3(32768 / 256), dim3(256), 0, stream,
                       pc1, pc2, knn);
    hipLaunchKernelGGL(feat_kernel, dim3(32768 / TP), dim3(256), 0, stream,
                       pc1, pc2, feat1, feat2, pos_w, pos_b,
                       w0, b0, w1, b1, t1w, t1b, t2w, t2b, knn, out);
}

// Round 2
// 689.485 us; speedup vs baseline: 2.1240x; 2.1240x over previous
//
#include <hip/hip_runtime.h>

#define NPTS 8192
#define KNNK 16
#define NSLOT 17          // keep 17, fp64-refine drops the worst -> robust 16-set
#define LEAKY 0.1f
#define TP 4              // points per block in feature kernel

// KNN kernel config
#define QPB 32                 // queries per block
#define KTHREADS 512           // threads per block (8 waves)
#define CHUNKS 16              // candidate chunks per query (threads per query)
#define CHLEN (NPTS / CHUNKS)  // 512 candidates per chunk
#define BUFCAP 96              // survivor buffer per query

// ---------------------------------------------------------------------------
// Kernel 1: exact KNN via threshold filter.
//   Phase 1: per (query,chunk) thread keeps 2 smallest distances (branchless).
//   Threshold = 17th smallest of the 32 collected values (>=17 survivors).
//   Phase 2: rescan, collect survivors d<=t into LDS buffer (rare appends).
//   Phase 3: exact top-17 of survivors + fp64 refine (same set as R1 kernel).
// ---------------------------------------------------------------------------
__global__ __launch_bounds__(KTHREADS) void knn_kernel(
    const float* __restrict__ pc1, const float* __restrict__ pc2,
    int* __restrict__ knn_out)
{
    __shared__ float sx[NPTS], sy[NPTS], sz[NPTS];   // candidate SoA (96 KB)
    __shared__ float m2buf[QPB][2 * CHUNKS];
    __shared__ float sthr[QPB];
    __shared__ int   scnt[QPB];
    __shared__ float survd[QPB][BUFCAP];
    __shared__ int   survi[QPB][BUFCAP];

    const int t   = threadIdx.x;
    const int q0  = blockIdx.x * QPB;            // first global query id
    const int dir = q0 >> 14;                    // uniform per block
    const int b   = (q0 >> 13) & 1;

    const float* __restrict__ pq    = dir ? pc2 : pc1;
    const float* __restrict__ pcand = dir ? pc1 : pc2;

    // stage candidate cloud for this (dir,b) as SoA
    const float* src = pcand + (size_t)b * NPTS * 3;
    for (int i = t; i < NPTS; i += KTHREADS) {
        sx[i] = src[3 * i];
        sy[i] = src[3 * i + 1];
        sz[i] = src[3 * i + 2];
    }
    if (t < QPB) scnt[t] = 0;
    __syncthreads();

    const int ql = t >> 4;                       // local query 0..31
    const int ch = t & 15;                       // chunk 0..15
    const int n0 = (q0 & (NPTS - 1));
    const float* qp = pq + ((size_t)b * NPTS + n0 + ql) * 3;
    const float qx = qp[0], qy = qp[1], qz = qp[2];

    // ---- phase 1: two smallest distances of this chunk, branchless --------
    float m1 = 3.0e38f, m2 = 3.0e38f;
    #pragma unroll 8
    for (int j = 0; j < CHLEN; ++j) {
        const int idx = j * CHUNKS + ch;         // interleaved: conflict-free
        const float dx = sx[idx] - qx;
        const float dy = sy[idx] - qy;
        const float dz = sz[idx] - qz;
        const float d  = fmaf(dx, dx, fmaf(dy, dy, dz * dz));
        const float nm2 = fminf(m2, fmaxf(m1, d));   // median3(m1,m2,d), m1<=m2
        m1 = fminf(m1, d);
        m2 = nm2;
    }
    m2buf[ql][2 * ch]     = m1;
    m2buf[ql][2 * ch + 1] = m2;
    __syncthreads();

    // ---- threshold: value of rank 16 (17th smallest) among 32 collected ---
    {
        const float v0 = m2buf[ql][2 * ch];
        const float v1 = m2buf[ql][2 * ch + 1];
        int r0 = 0, r1 = 0;
        #pragma unroll
        for (int jj = 0; jj < 2 * CHUNKS; ++jj) {
            const float vj = m2buf[ql][jj];
            r0 += (vj < v0 || (vj == v0 && jj < 2 * ch)) ? 1 : 0;
            r1 += (vj < v1 || (vj == v1 && jj < 2 * ch + 1)) ? 1 : 0;
        }
        if (r0 == 16) sthr[ql] = v0;
        if (r1 == 16) sthr[ql] = v1;
    }
    __syncthreads();

    // ---- phase 2: collect survivors (identical fp32 arithmetic) -----------
    {
        const float tq = sthr[ql];
        #pragma unroll 4
        for (int j = 0; j < CHLEN; ++j) {
            const int idx = j * CHUNKS + ch;
            const float dx = sx[idx] - qx;
            const float dy = sy[idx] - qy;
            const float dz = sz[idx] - qz;
            const float d  = fmaf(dx, dx, fmaf(dy, dy, dz * dz));
            if (d <= tq) {
                const int pos = atomicAdd(&scnt[ql], 1);
                if (pos < BUFCAP) { survd[ql][pos] = d; survi[ql][pos] = idx; }
            }
        }
    }
    __syncthreads();

    // ---- phase 3: exact top-17 of survivors + fp64 refine, one thread/query
    if (t < QPB) {
        const int nc = min(scnt[t], BUFCAP);

        float dist[NSLOT];   // sorted descending by (d, idx); dist[0] = worst
        int   ind[NSLOT];
        #pragma unroll
        for (int i = 0; i < NSLOT; ++i) { dist[i] = 3.0e38f; ind[i] = 0x7fffffff; }

        for (int s = 0; s < nc; ++s) {
            const float d  = survd[t][s];
            const int   id = survi[t][s];
            const bool better0 = (d < dist[0]) || (d == dist[0] && id < ind[0]);
            if (better0) {
                bool cprev = true;
                #pragma unroll
                for (int i = 0; i < NSLOT - 1; ++i) {
                    const bool ci = (d < dist[i + 1]) ||
                                    (d == dist[i + 1] && id < ind[i + 1]);
                    const float nv = ci ? dist[i + 1] : (cprev ? d  : dist[i]);
                    const int   ni = ci ? ind[i + 1]  : (cprev ? id : ind[i]);
                    dist[i] = nv; ind[i] = ni;
                    cprev = ci;
                }
                if (cprev) { dist[NSLOT - 1] = d; ind[NSLOT - 1] = id; }
            }
        }

        // fp64 refine: drop the farthest of the 17 by exact distance
        const float* qpp = pq + ((size_t)b * NPTS + n0 + t) * 3;
        const double dqx = (double)qpp[0], dqy = (double)qpp[1], dqz = (double)qpp[2];
        double dd[NSLOT];
        #pragma unroll
        for (int i = 0; i < NSLOT; ++i) {
            const int id = ind[i];
            const double dx = (double)sx[id] - dqx;
            const double dy = (double)sy[id] - dqy;
            const double dz = (double)sz[id] - dqz;
            dd[i] = dx * dx + dy * dy + dz * dz;
        }
        int worst = 0; double wd = dd[0];
        #pragma unroll
        for (int i = 1; i < NSLOT; ++i) { if (dd[i] > wd) { wd = dd[i]; worst = i; } }

        int* outp = knn_out + (size_t)(q0 + t) * KNNK;
        int slot = 0;
        #pragma unroll
        for (int i = 0; i < NSLOT; ++i) {
            if (i != worst) outp[slot++] = ind[i];
        }
    }
}

// ---------------------------------------------------------------------------
// Kernel 2: fused gather + pos-MLP + 2x (64x64 leaky MLP) + max-pool + 64->128
// Block = 256 threads = 4 point-groups x 64 channel-threads. LDS tiles with
// +4 row padding (stride 68) to keep bank conflicts <= 2-way.
// ---------------------------------------------------------------------------
__device__ __forceinline__ void mlp_layer(
    const float (* __restrict__ in)[68], float (* __restrict__ outp)[68],
    const float (* __restrict__ w)[68], const float* __restrict__ bias, int c)
{
    const int c0 = c & 15;
    const int kb = (c >> 4) * 4;
    float acc[4][4];
#pragma unroll
    for (int kk = 0; kk < 4; ++kk)
#pragma unroll
        for (int j = 0; j < 4; ++j) acc[kk][j] = 0.f;

#pragma unroll
    for (int cc = 0; cc < 64; cc += 4) {
        float4 wv[4];
#pragma unroll
        for (int j = 0; j < 4; ++j)
            wv[j] = *(const float4*)&w[c0 + 16 * j][cc];
#pragma unroll
        for (int kk = 0; kk < 4; ++kk) {
            const float4 av = *(const float4*)&in[kb + kk][cc];
#pragma unroll
            for (int j = 0; j < 4; ++j) {
                acc[kk][j] = fmaf(av.x, wv[j].x, acc[kk][j]);
                acc[kk][j] = fmaf(av.y, wv[j].y, acc[kk][j]);
                acc[kk][j] = fmaf(av.z, wv[j].z, acc[kk][j]);
                acc[kk][j] = fmaf(av.w, wv[j].w, acc[kk][j]);
            }
        }
    }
#pragma unroll
    for (int kk = 0; kk < 4; ++kk)
#pragma unroll
        for (int j = 0; j < 4; ++j) {
            float v = acc[kk][j] + bias[c0 + 16 * j];
            v = v >= 0.f ? v : LEAKY * v;
            outp[kb + kk][c0 + 16 * j] = v;
        }
}

__global__ __launch_bounds__(256) void feat_kernel(
    const float* __restrict__ pc1, const float* __restrict__ pc2,
    const float* __restrict__ feat1, const float* __restrict__ feat2,
    const float* __restrict__ pos_w, const float* __restrict__ pos_b,
    const float* __restrict__ w0, const float* __restrict__ b0,
    const float* __restrict__ w1, const float* __restrict__ b1,
    const float* __restrict__ t1w, const float* __restrict__ t1b,
    const float* __restrict__ t2w, const float* __restrict__ t2b,
    const int* __restrict__ knn, float* __restrict__ out)
{
    __shared__ __align__(16) float sw0[64][68];
    __shared__ __align__(16) float sw1[64][68];
    __shared__ __align__(16) float tA[TP][16][68];
    __shared__ __align__(16) float tB[TP][16][68];
    __shared__ float sposw[3][64];
    __shared__ float sposb[64], sb0[64], sb1[64];
    __shared__ int   snidx[TP][16];
    __shared__ float sdir[TP][16][3];
    __shared__ __align__(16) float smax[TP][68];

    const int t = threadIdx.x;
    for (int i = t; i < 4096; i += 256) {
        sw0[i >> 6][i & 63] = w0[i];
        sw1[i >> 6][i & 63] = w1[i];
    }
    if (t < 64) {
        sposb[t] = pos_b[t]; sb0[t] = b0[t]; sb1[t] = b1[t];
        sposw[0][t] = pos_w[t * 3 + 0];
        sposw[1][t] = pos_w[t * 3 + 1];
        sposw[2][t] = pos_w[t * 3 + 2];
    }

    const int g = t >> 6, c = t & 63;
    const int p = blockIdx.x * TP + g;               // 0..32767
    const int dir = p >> 14, b = (p >> 13) & 1, n = p & (NPTS - 1);

    const float* pq = dir ? pc2 : pc1;
    const float* pc = dir ? pc1 : pc2;
    const float* fq = dir ? feat2 : feat1;
    const float* fc = dir ? feat1 : feat2;
    const float* tw = dir ? t2w : t1w;
    const float* tb = dir ? t2b : t1b;

    if (c < 16) {
        const int id = knn[(size_t)p * KNNK + c];
        snidx[g][c] = id;
        const float* qp  = pq + ((size_t)b * NPTS + n) * 3;
        const float* nbp = pc + ((size_t)b * NPTS + id) * 3;
        sdir[g][c][0] = nbp[0] - qp[0];
        sdir[g][c][1] = nbp[1] - qp[1];
        sdir[g][c][2] = nbp[2] - qp[2];
    }
    __syncthreads();

    // initial layer: leaky(g2 + p1 + pos_feat)
    {
        const float fqc = fq[((size_t)b * NPTS + n) * 64 + c];
        const float base = sposb[c] + fqc;
        const float pw0 = sposw[0][c], pw1 = sposw[1][c], pw2 = sposw[2][c];
#pragma unroll
        for (int k = 0; k < 16; ++k) {
            const int id = snidx[g][k];
            const float gf = fc[((size_t)b * NPTS + id) * 64 + c];
            float v = gf + base;
            v = fmaf(sdir[g][k][0], pw0, v);
            v = fmaf(sdir[g][k][1], pw1, v);
            v = fmaf(sdir[g][k][2], pw2, v);
            v = v >= 0.f ? v : LEAKY * v;
            tA[g][k][c] = v;
        }
    }
    __syncthreads();

    mlp_layer(tA[g], tB[g], sw0, sb0, c);
    __syncthreads();
    mlp_layer(tB[g], tA[g], sw1, sb1, c);
    __syncthreads();

    // max-pool over 16 neighbors
    {
        float m = tA[g][0][c];
#pragma unroll
        for (int k = 1; k < 16; ++k) m = fmaxf(m, tA[g][k][c]);
        smax[g][c] = m;
    }
    __syncthreads();

    // final 64 -> 128 linear (no activation); thread c -> outputs c, c+64
    {
        float acc0 = tb[c];
        float acc1 = tb[c + 64];
#pragma unroll
        for (int cc = 0; cc < 64; cc += 4) {
            const float4 mv = *(const float4*)&smax[g][cc];
            const float4 wa = *(const float4*)&tw[(size_t)c * 64 + cc];
            const float4 wb = *(const float4*)&tw[(size_t)(c + 64) * 64 + cc];
            acc0 = fmaf(mv.x, wa.x, acc0); acc0 = fmaf(mv.y, wa.y, acc0);
            acc0 = fmaf(mv.z, wa.z, acc0); acc0 = fmaf(mv.w, wa.w, acc0);
            acc1 = fmaf(mv.x, wb.x, acc1); acc1 = fmaf(mv.y, wb.y, acc1);
            acc1 = fmaf(mv.z, wb.z, acc1); acc1 = fmaf(mv.w, wb.w, acc1);
        }
        float* op = out + (size_t)dir * (2 * NPTS * 128)
                        + ((size_t)b * NPTS + n) * 128;
        op[c]      = acc0;
        op[c + 64] = acc1;
    }
}

// ---------------------------------------------------------------------------
extern "C" void kernel_launch(void* const* d_in, const int* in_sizes, int n_in,
                              void* d_out, int out_size, void* d_ws, size_t ws_size,
                              hipStream_t stream)
{
    const float* pc1   = (const float*)d_in[0];
    const float* pc2   = (const float*)d_in[1];
    const float* feat1 = (const float*)d_in[2];
    const float* feat2 = (const float*)d_in[3];
    const float* pos_w = (const float*)d_in[4];
    const float* pos_b = (const float*)d_in[5];
    const float* w0    = (const float*)d_in[6];
    const float* b0    = (const float*)d_in[7];
    const float* w1    = (const float*)d_in[8];
    const float* b1    = (const float*)d_in[9];
    const float* t1w   = (const float*)d_in[10];
    const float* t1b   = (const float*)d_in[11];
    const float* t2w   = (const float*)d_in[12];
    const float* t2b   = (const float*)d_in[13];

    int*   knn = (int*)d_ws;          // 32768 * 16 ints = 2 MB scratch
    float* out = (float*)d_out;

    hipLaunchKernelGGL(knn_kernel, dim3(32768 / QPB), dim3(KTHREADS), 0, stream,
                       pc1, pc2, knn);
    hipLaunchKernelGGL(feat_kernel, dim3(32768 / TP), dim3(256), 0, stream,
                       pc1, pc2, feat1, feat2, pos_w, pos_b,
                       w0, b0, w1, b1, t1w, t1b, t2w, t2b, knn, out);
}

// Round 3
// 568.800 us; speedup vs baseline: 2.5747x; 1.2122x over previous
//
#include <hip/hip_runtime.h>

#define NPTS 8192
#define KNNK 16
#define NSLOT 17          // keep 17, fp64-refine drops the worst -> robust 16-set
#define LEAKY 0.1f

// ---- knn config ----
#define KTH   512              // threads/block (8 waves)
#define QPB   128              // queries per block -> grid 256
#define CHN   32               // chunks (threads) per query
#define GQ    8                // queries per thread
#define JLEN  (NPTS / CHN)     // 256 candidates per chunk
#define BUFCAP 48              // survivor buffer per query

// ---------------------------------------------------------------------------
// Kernel 1: exact KNN, query-register-blocked threshold filter.
//   Thread = (chunk ch, query-group qg); owns GQ=8 queries, scans 256 cands.
//   Phase 1: per (thread,query) keep 2 smallest (branchless min2) ->
//            64 collected true distances per query across its 32 chunks.
//   Threshold: exact rank-17 of the 64 via __shfl rank in 32-lane segments.
//   Phase 2: rescan (identical fp32 math), append d<=t survivors (rare).
//   Phase 3: exact top-17 of survivors + fp64 refine -> same set as R1/R2.
// ---------------------------------------------------------------------------
__global__ __launch_bounds__(KTH) void knn_kernel(
    const float* __restrict__ pc1, const float* __restrict__ pc2,
    int* __restrict__ knn_out)
{
    __shared__ float sx[NPTS], sy[NPTS], sz[NPTS];   // 96 KB candidate SoA
    __shared__ float survd[QPB][BUFCAP];             // 24 KB
    __shared__ int   survi[QPB][BUFCAP];             // 24 KB
    __shared__ float sthr[QPB];
    __shared__ int   scnt[QPB];

    const int t   = threadIdx.x;
    const int q0  = blockIdx.x * QPB;
    const int dir = q0 >> 14;
    const int b   = (q0 >> 13) & 1;

    const float* __restrict__ pq    = dir ? pc2 : pc1;
    const float* __restrict__ pcand = dir ? pc1 : pc2;

    const float* src = pcand + (size_t)b * NPTS * 3;
    for (int i = t; i < NPTS; i += KTH) {
        sx[i] = src[3 * i];
        sy[i] = src[3 * i + 1];
        sz[i] = src[3 * i + 2];
    }
    if (t < QPB) scnt[t] = 0;
    __syncthreads();

    const int ch = t & (CHN - 1);      // chunk 0..31 (lane-in-segment)
    const int qg = t >> 5;             // query group 0..15 (8 queries each)
    const int n0 = q0 & (NPTS - 1);

    float qx[GQ], qy[GQ], qz[GQ];
    #pragma unroll
    for (int g = 0; g < GQ; ++g) {
        const float* qp = pq + ((size_t)b * NPTS + n0 + qg * GQ + g) * 3;
        qx[g] = qp[0]; qy[g] = qp[1]; qz[g] = qp[2];
    }

    // ---- phase 1: min-2 per (thread,query), branchless ---------------------
    float m1[GQ], m2[GQ];
    #pragma unroll
    for (int g = 0; g < GQ; ++g) { m1[g] = 3.0e38f; m2[g] = 3.0e38f; }

    #pragma unroll 2
    for (int j = 0; j < JLEN; ++j) {
        const int idx = j * CHN + ch;            // consecutive -> all 32 banks
        const float cx = sx[idx], cy = sy[idx], cz = sz[idx];
        #pragma unroll
        for (int g = 0; g < GQ; ++g) {
            const float dx = cx - qx[g];
            const float dy = cy - qy[g];
            const float dz = cz - qz[g];
            const float d  = fmaf(dx, dx, fmaf(dy, dy, dz * dz));
            m2[g] = fminf(m2[g], fmaxf(m1[g], d));   // median3 keeps 2nd-min
            m1[g] = fminf(m1[g], d);
        }
    }

    // ---- threshold: rank-17 (0-based 16) of the 64 values per query --------
    // Query q's 64 values live (m1,m2) per lane across its 32-lane segment.
    #pragma unroll
    for (int g = 0; g < GQ; ++g) {
        int r1 = 0, r2 = 0;                      // ranks of m1[g], m2[g]
        for (int j = 0; j < CHN; ++j) {
            const float v1 = __shfl(m1[g], j, 32);
            const float v2 = __shfl(m2[g], j, 32);
            r1 += (v1 < m1[g] || (v1 == m1[g] && 2 * j     < 2 * ch)) ? 1 : 0;
            r1 += (v2 < m1[g] || (v2 == m1[g] && 2 * j + 1 < 2 * ch)) ? 1 : 0;
            r2 += (v1 < m2[g] || (v1 == m2[g] && 2 * j     < 2 * ch + 1)) ? 1 : 0;
            r2 += (v2 < m2[g] || (v2 == m2[g] && 2 * j + 1 < 2 * ch + 1)) ? 1 : 0;
        }
        if (r1 == 16) sthr[qg * GQ + g] = m1[g];
        if (r2 == 16) sthr[qg * GQ + g] = m2[g];
    }
    __builtin_amdgcn_wave_barrier();   // writer/readers are the same wave

    // ---- phase 2: collect survivors (identical fp32 arithmetic) ------------
    float tq[GQ];
    #pragma unroll
    for (int g = 0; g < GQ; ++g) tq[g] = sthr[qg * GQ + g];

    #pragma unroll 2
    for (int j = 0; j < JLEN; ++j) {
        const int idx = j * CHN + ch;
        const float cx = sx[idx], cy = sy[idx], cz = sz[idx];
        #pragma unroll
        for (int g = 0; g < GQ; ++g) {
            const float dx = cx - qx[g];
            const float dy = cy - qy[g];
            const float dz = cz - qz[g];
            const float d  = fmaf(dx, dx, fmaf(dy, dy, dz * dz));
            if (d <= tq[g]) {
                const int q = qg * GQ + g;
                const int pos = atomicAdd(&scnt[q], 1);
                if (pos < BUFCAP) { survd[q][pos] = d; survi[q][pos] = idx; }
            }
        }
    }
    __syncthreads();

    // ---- phase 3: exact top-17 of survivors + fp64 refine ------------------
    if (t < QPB) {
        const int nc = min(scnt[t], BUFCAP);

        float dist[NSLOT];   // sorted descending by (d, idx); dist[0] = worst
        int   ind[NSLOT];
        #pragma unroll
        for (int i = 0; i < NSLOT; ++i) { dist[i] = 3.0e38f; ind[i] = 0x7fffffff; }

        for (int s = 0; s < nc; ++s) {
            const float d  = survd[t][s];
            const int   id = survi[t][s];
            const bool better0 = (d < dist[0]) || (d == dist[0] && id < ind[0]);
            if (better0) {
                bool cprev = true;
                #pragma unroll
                for (int i = 0; i < NSLOT - 1; ++i) {
                    const bool ci = (d < dist[i + 1]) ||
                                    (d == dist[i + 1] && id < ind[i + 1]);
                    const float nv = ci ? dist[i + 1] : (cprev ? d  : dist[i]);
                    const int   ni = ci ? ind[i + 1]  : (cprev ? id : ind[i]);
                    dist[i] = nv; ind[i] = ni;
                    cprev = ci;
                }
                if (cprev) { dist[NSLOT - 1] = d; ind[NSLOT - 1] = id; }
            }
        }

        const float* qpp = pq + ((size_t)b * NPTS + n0 + t) * 3;
        const double dqx = (double)qpp[0], dqy = (double)qpp[1], dqz = (double)qpp[2];
        double dd[NSLOT];
        #pragma unroll
        for (int i = 0; i < NSLOT; ++i) {
            const int id = ind[i];
            const double dx = (double)sx[id] - dqx;
            const double dy = (double)sy[id] - dqy;
            const double dz = (double)sz[id] - dqz;
            dd[i] = dx * dx + dy * dy + dz * dz;
        }
        int worst = 0; double wd = dd[0];
        #pragma unroll
        for (int i = 1; i < NSLOT; ++i) { if (dd[i] > wd) { wd = dd[i]; worst = i; } }

        int* outp = knn_out + (size_t)(q0 + t) * KNNK;
        int slot = 0;
        #pragma unroll
        for (int i = 0; i < NSLOT; ++i) {
            if (i != worst) outp[slot++] = ind[i];
        }
    }
}

// ---------------------------------------------------------------------------
// Kernel 2: feature MLP, barrier-free wave streaming.
// 512 blocks x 256 thr (4 waves). Wave w streams 16 points through a private
// in-place LDS tile (per-wave LDS ops are in-order; wave_barrier pins the
// compiler's ordering). Next point's gathers are prefetched during MLP.
// ---------------------------------------------------------------------------
#define FW   4
#define FPPW 16

__device__ __forceinline__ void wave_layer(
    float (* __restrict__ tile)[68], const float (* __restrict__ w)[68],
    const float* __restrict__ bb, int c)
{
    const int c0 = c & 15;
    const int kb = (c >> 4) * 4;
    float acc[4][4];
    #pragma unroll
    for (int kk = 0; kk < 4; ++kk)
        #pragma unroll
        for (int j = 0; j < 4; ++j) acc[kk][j] = 0.f;

    #pragma unroll
    for (int cc = 0; cc < 64; cc += 4) {
        float4 wv[4];
        #pragma unroll
        for (int j = 0; j < 4; ++j)
            wv[j] = *(const float4*)&w[c0 + 16 * j][cc];
        #pragma unroll
        for (int kk = 0; kk < 4; ++kk) {
            const float4 av = *(const float4*)&tile[kb + kk][cc];
            #pragma unroll
            for (int j = 0; j < 4; ++j) {
                acc[kk][j] = fmaf(av.x, wv[j].x, acc[kk][j]);
                acc[kk][j] = fmaf(av.y, wv[j].y, acc[kk][j]);
                acc[kk][j] = fmaf(av.z, wv[j].z, acc[kk][j]);
                acc[kk][j] = fmaf(av.w, wv[j].w, acc[kk][j]);
            }
        }
    }
    __builtin_amdgcn_wave_barrier();   // all reads before in-place writes
    #pragma unroll
    for (int kk = 0; kk < 4; ++kk)
        #pragma unroll
        for (int j = 0; j < 4; ++j) {
            float v = acc[kk][j] + bb[j];
            v = v >= 0.f ? v : LEAKY * v;
            tile[kb + kk][c0 + 16 * j] = v;
        }
}

__global__ __launch_bounds__(256) void feat_kernel(
    const float* __restrict__ pc1, const float* __restrict__ pc2,
    const float* __restrict__ feat1, const float* __restrict__ feat2,
    const float* __restrict__ pos_w, const float* __restrict__ pos_b,
    const float* __restrict__ w0, const float* __restrict__ b0,
    const float* __restrict__ w1, const float* __restrict__ b1,
    const float* __restrict__ t1w, const float* __restrict__ t1b,
    const float* __restrict__ t2w, const float* __restrict__ t2b,
    const int* __restrict__ knn, float* __restrict__ out)
{
    __shared__ __align__(16) float sw0[64][68];       // 17.4 KB
    __shared__ __align__(16) float sw1[64][68];       // 17.4 KB
    __shared__ __align__(16) float tA[FW][16][68];    // 17.4 KB
    __shared__ __align__(16) float sdir[FW][2][16][4];// 2 KB (double-buffered)
    __shared__ __align__(16) float sm[64][64];        // 16 KB max-pooled feats

    const int t  = threadIdx.x;
    const int w  = t >> 6;
    const int c  = t & 63;
    const int p0 = blockIdx.x * 64;                   // 64 points per block
    const int dir = p0 >> 14, bb = (p0 >> 13) & 1;
    const int n0 = p0 & (NPTS - 1);

    const float* __restrict__ pqd = dir ? pc2 : pc1;
    const float* __restrict__ pcd = dir ? pc1 : pc2;
    const float* __restrict__ fqd = dir ? feat2 : feat1;
    const float* __restrict__ fcd = dir ? feat1 : feat2;

    for (int i = t; i < 4096; i += 256) {
        sw0[i >> 6][i & 63] = w0[i];
        sw1[i >> 6][i & 63] = w1[i];
    }

    const float pbc  = pos_b[c];
    const float pw0c = pos_w[3 * c], pw1c = pos_w[3 * c + 1], pw2c = pos_w[3 * c + 2];
    const int c0 = c & 15;
    float bb0[4], bb1[4];
    #pragma unroll
    for (int j = 0; j < 4; ++j) { bb0[j] = b0[c0 + 16 * j]; bb1[j] = b1[c0 + 16 * j]; }
    __syncthreads();

    float gf[KNNK], ngf[KNNK], fqv, nfq;

    // prefetch: ids + neighbor dirs (LDS slot i&1) + gathered feats (regs)
    auto do_prefetch = [&](int i, float* dst, float* dfq) {
        const int pl = w * FPPW + i;
        const int n  = n0 + pl;
        const int idv = knn[((size_t)(p0 + pl)) * KNNK + (c & 15)];
        if (c < 16) {
            const float* nbp = pcd + ((size_t)bb * NPTS + idv) * 3;
            const float* qp  = pqd + ((size_t)bb * NPTS + n) * 3;
            float4 dv;
            dv.x = nbp[0] - qp[0];
            dv.y = nbp[1] - qp[1];
            dv.z = nbp[2] - qp[2];
            dv.w = 0.f;
            *(float4*)&sdir[w][i & 1][c][0] = dv;
        }
        *dfq = fqd[((size_t)bb * NPTS + n) * 64 + c];
        #pragma unroll
        for (int k = 0; k < KNNK; ++k) {
            const int idk = __shfl(idv, k, 64);
            dst[k] = fcd[((size_t)bb * NPTS + idk) * 64 + c];
        }
    };

    do_prefetch(0, ngf, &nfq);

    for (int i = 0; i < FPPW; ++i) {
        #pragma unroll
        for (int k = 0; k < KNNK; ++k) gf[k] = ngf[k];
        fqv = nfq;
        __builtin_amdgcn_wave_barrier();
        if (i + 1 < FPPW) do_prefetch(i + 1, ngf, &nfq);

        // initial layer: leaky(g2 + p1 + pos_feat) -> tile
        const float base = fqv + pbc;
        #pragma unroll
        for (int k = 0; k < KNNK; ++k) {
            const float4 dv = *(const float4*)&sdir[w][i & 1][k][0];
            float v = gf[k] + base;
            v = fmaf(dv.x, pw0c, v);
            v = fmaf(dv.y, pw1c, v);
            v = fmaf(dv.z, pw2c, v);
            v = v >= 0.f ? v : LEAKY * v;
            tA[w][k][c] = v;
        }
        __builtin_amdgcn_wave_barrier();

        wave_layer(tA[w], sw0, bb0, c);
        __builtin_amdgcn_wave_barrier();
        wave_layer(tA[w], sw1, bb1, c);
        __builtin_amdgcn_wave_barrier();

        float m = tA[w][0][c];
        #pragma unroll
        for (int k = 1; k < KNNK; ++k) m = fmaxf(m, tA[w][k][c]);
        sm[w * FPPW + i][c] = m;
        __builtin_amdgcn_wave_barrier();
    }
    __syncthreads();

    // final 64->128 linear, block-wide: thread -> (o = t&127, pg = t>>7)
    {
        const float* __restrict__ tw = dir ? t2w : t1w;
        const float* __restrict__ tb = dir ? t2b : t1b;
        const int o  = t & 127;
        const int pg = t >> 7;
        float twr[64];
        #pragma unroll
        for (int cc = 0; cc < 64; cc += 4)
            *(float4*)&twr[cc] = *(const float4*)&tw[(size_t)o * 64 + cc];
        const float tbo = tb[o];
        float* op = out + (size_t)dir * (2 * NPTS * 128);

        #pragma unroll 4
        for (int pp = 0; pp < 32; ++pp) {
            const int pl = pg * 32 + pp;
            float acc = tbo;
            #pragma unroll
            for (int cc = 0; cc < 64; cc += 4) {
                const float4 mv = *(const float4*)&sm[pl][cc];
                acc = fmaf(mv.x, twr[cc],     acc);
                acc = fmaf(mv.y, twr[cc + 1], acc);
                acc = fmaf(mv.z, twr[cc + 2], acc);
                acc = fmaf(mv.w, twr[cc + 3], acc);
            }
            op[((size_t)bb * NPTS + n0 + pl) * 128 + o] = acc;
        }
    }
}

// ---------------------------------------------------------------------------
extern "C" void kernel_launch(void* const* d_in, const int* in_sizes, int n_in,
                              void* d_out, int out_size, void* d_ws, size_t ws_size,
                              hipStream_t stream)
{
    const float* pc1   = (const float*)d_in[0];
    const float* pc2   = (const float*)d_in[1];
    const float* feat1 = (const float*)d_in[2];
    const float* feat2 = (const float*)d_in[3];
    const float* pos_w = (const float*)d_in[4];
    const float* pos_b = (const float*)d_in[5];
    const float* w0    = (const float*)d_in[6];
    const float* b0    = (const float*)d_in[7];
    const float* w1    = (const float*)d_in[8];
    const float* b1    = (const float*)d_in[9];
    const float* t1w   = (const float*)d_in[10];
    const float* t1b   = (const float*)d_in[11];
    const float* t2w   = (const float*)d_in[12];
    const float* t2b   = (const float*)d_in[13];

    int*   knn = (int*)d_ws;          // 32768 * 16 ints = 2 MB scratch
    float* out = (float*)d_out;

    hipLaunchKernelGGL(knn_kernel, dim3(32768 / QPB), dim3(KTH), 0, stream,
                       pc1, pc2, knn);
    hipLaunchKernelGGL(feat_kernel, dim3(32768 / 64), dim3(256), 0, stream,
                       pc1, pc2, feat1, feat2, pos_w, pos_b,
                       w0, b0, w1, b1, t1w, t1b, t2w, t2b, knn, out);
}

// Round 4
// 411.304 us; speedup vs baseline: 3.5606x; 1.3829x over previous
//
#include <hip/hip_runtime.h>

#define NPTS 8192
#define KNNK 16
#define NSLOT 17          // keep 17, fp64-refine drops the worst -> robust 16-set
#define LEAKY 0.1f

typedef short bf16x8 __attribute__((ext_vector_type(8)));
typedef float f32x4  __attribute__((ext_vector_type(4)));

// ---- knn config ----
#define KTH   512              // threads/block (8 waves)
#define QPB   128              // queries per block -> grid 256
#define CHN   32               // chunks (threads) per query
#define GQ    8                // queries per thread
#define JLEN  (NPTS / CHN)     // 256 candidates per chunk
#define BUFCAP 48              // survivor buffer per query

// ---------------------------------------------------------------------------
// Kernel 1: exact KNN, query-register-blocked threshold filter.
// R4 change: rank-17 threshold via unrolled LDS-broadcast table (R2-proven)
// instead of serial __shfl(bpermute) chains. Distance math unchanged.
// ---------------------------------------------------------------------------
__global__ __launch_bounds__(KTH) void knn_kernel(
    const float* __restrict__ pc1, const float* __restrict__ pc2,
    int* __restrict__ knn_out)
{
    __shared__ float sx[NPTS], sy[NPTS], sz[NPTS];   // 96 KB candidate SoA
    // per-query row of 96 floats: [0..47] survd, [48..95] survi (as int).
    // cols [0..63] double as the rank table before phase 2 (wave-local).
    __shared__ float sbuf[QPB][2 * BUFCAP];          // 48 KB
    __shared__ float sthr[QPB];
    __shared__ int   scnt[QPB];

    const int t   = threadIdx.x;
    const int q0  = blockIdx.x * QPB;
    const int dir = q0 >> 14;
    const int b   = (q0 >> 13) & 1;

    const float* __restrict__ pq    = dir ? pc2 : pc1;
    const float* __restrict__ pcand = dir ? pc1 : pc2;

    const float* src = pcand + (size_t)b * NPTS * 3;
    for (int i = t; i < NPTS; i += KTH) {
        sx[i] = src[3 * i];
        sy[i] = src[3 * i + 1];
        sz[i] = src[3 * i + 2];
    }
    if (t < QPB) scnt[t] = 0;
    __syncthreads();

    const int ch = t & (CHN - 1);      // chunk 0..31
    const int qg = t >> 5;             // query group 0..15 (8 queries each)
    const int n0 = q0 & (NPTS - 1);

    float qx[GQ], qy[GQ], qz[GQ];
    #pragma unroll
    for (int g = 0; g < GQ; ++g) {
        const float* qp = pq + ((size_t)b * NPTS + n0 + qg * GQ + g) * 3;
        qx[g] = qp[0]; qy[g] = qp[1]; qz[g] = qp[2];
    }

    // ---- phase 1: min-2 per (thread,query), branchless ---------------------
    float m1[GQ], m2[GQ];
    #pragma unroll
    for (int g = 0; g < GQ; ++g) { m1[g] = 3.0e38f; m2[g] = 3.0e38f; }

    #pragma unroll 4
    for (int j = 0; j < JLEN; ++j) {
        const int idx = j * CHN + ch;
        const float cx = sx[idx], cy = sy[idx], cz = sz[idx];
        #pragma unroll
        for (int g = 0; g < GQ; ++g) {
            const float dx = cx - qx[g];
            const float dy = cy - qy[g];
            const float dz = cz - qz[g];
            const float d  = fmaf(dx, dx, fmaf(dy, dy, dz * dz));
            m2[g] = fminf(m2[g], fmaxf(m1[g], d));   // median3 keeps 2nd-min
            m1[g] = fminf(m1[g], d);
        }
    }

    // ---- threshold: rank-16 (0-based) of 64 collected, LDS rank table ------
    #pragma unroll
    for (int g = 0; g < GQ; ++g) {
        const int row = qg * GQ + g;
        sbuf[row][2 * ch]     = m1[g];
        sbuf[row][2 * ch + 1] = m2[g];
    }
    __builtin_amdgcn_wave_barrier();   // table rows are wave-local

    #pragma unroll
    for (int g = 0; g < GQ; ++g) {
        const int row = qg * GQ + g;
        const float v1 = m1[g], v2 = m2[g];
        int r1 = 0, r2 = 0;
        #pragma unroll
        for (int jj = 0; jj < 2 * CHN; ++jj) {
            const float vj = sbuf[row][jj];
            r1 += (vj < v1 || (vj == v1 && jj < 2 * ch)) ? 1 : 0;
            r2 += (vj < v2 || (vj == v2 && jj < 2 * ch + 1)) ? 1 : 0;
        }
        if (r1 == 16) sthr[row] = v1;
        if (r2 == 16) sthr[row] = v2;
    }
    __builtin_amdgcn_wave_barrier();

    // ---- phase 2: collect survivors (identical fp32 arithmetic) ------------
    float tq[GQ];
    #pragma unroll
    for (int g = 0; g < GQ; ++g) tq[g] = sthr[qg * GQ + g];

    #pragma unroll 4
    for (int j = 0; j < JLEN; ++j) {
        const int idx = j * CHN + ch;
        const float cx = sx[idx], cy = sy[idx], cz = sz[idx];
        #pragma unroll
        for (int g = 0; g < GQ; ++g) {
            const float dx = cx - qx[g];
            const float dy = cy - qy[g];
            const float dz = cz - qz[g];
            const float d  = fmaf(dx, dx, fmaf(dy, dy, dz * dz));
            if (d <= tq[g]) {
                const int q = qg * GQ + g;
                const int pos = atomicAdd(&scnt[q], 1);
                if (pos < BUFCAP) {
                    sbuf[q][pos] = d;
                    ((int*)&sbuf[q][BUFCAP])[pos] = idx;
                }
            }
        }
    }
    __syncthreads();

    // ---- phase 3: exact top-17 of survivors + fp64 refine ------------------
    if (t < QPB) {
        const int nc = min(scnt[t], BUFCAP);

        float dist[NSLOT];   // sorted descending by (d, idx); dist[0] = worst
        int   ind[NSLOT];
        #pragma unroll
        for (int i = 0; i < NSLOT; ++i) { dist[i] = 3.0e38f; ind[i] = 0x7fffffff; }

        for (int s = 0; s < nc; ++s) {
            const float d  = sbuf[t][s];
            const int   id = ((int*)&sbuf[t][BUFCAP])[s];
            const bool better0 = (d < dist[0]) || (d == dist[0] && id < ind[0]);
            if (better0) {
                bool cprev = true;
                #pragma unroll
                for (int i = 0; i < NSLOT - 1; ++i) {
                    const bool ci = (d < dist[i + 1]) ||
                                    (d == dist[i + 1] && id < ind[i + 1]);
                    const float nv = ci ? dist[i + 1] : (cprev ? d  : dist[i]);
                    const int   ni = ci ? ind[i + 1]  : (cprev ? id : ind[i]);
                    dist[i] = nv; ind[i] = ni;
                    cprev = ci;
                }
                if (cprev) { dist[NSLOT - 1] = d; ind[NSLOT - 1] = id; }
            }
        }

        const float* qpp = pq + ((size_t)b * NPTS + n0 + t) * 3;
        const double dqx = (double)qpp[0], dqy = (double)qpp[1], dqz = (double)qpp[2];
        double dd[NSLOT];
        #pragma unroll
        for (int i = 0; i < NSLOT; ++i) {
            const int id = ind[i];
            const double dx = (double)sx[id] - dqx;
            const double dy = (double)sy[id] - dqy;
            const double dz = (double)sz[id] - dqz;
            dd[i] = dx * dx + dy * dy + dz * dz;
        }
        int worst = 0; double wd = dd[0];
        #pragma unroll
        for (int i = 1; i < NSLOT; ++i) { if (dd[i] > wd) { wd = dd[i]; worst = i; } }

        int* outp = knn_out + (size_t)(q0 + t) * KNNK;
        int slot = 0;
        #pragma unroll
        for (int i = 0; i < NSLOT; ++i) {
            if (i != worst) outp[slot++] = ind[i];
        }
    }
}

// ---------------------------------------------------------------------------
// Kernel 2: feature MLP via bf16x3-split MFMA.
// Block = 256 thr (4 waves) x FP=4 points. Wave w owns N-tile w (out-channels
// 16w..16w+15); its B-fragments (hi+lo, both layers) live in registers.
// Activations pass between layers as LDS u32 = (bf16hi<<16 | bf16lo),
// row stride 68 (2-way bank aliasing only = free).
// ---------------------------------------------------------------------------
#define FP 4

__device__ __forceinline__ unsigned int packhl(float f) {
    const unsigned int u = __float_as_uint(f);
    const unsigned int h = u & 0xffff0000u;
    const float lf = f - __uint_as_float(h);
    return h | (__float_as_uint(lf) >> 16);
}

__device__ __forceinline__ void build_b(const float* __restrict__ wrow,
                                        bf16x8* hi, bf16x8* lo) {
    union { unsigned int u[4]; bf16x8 v; } H, L;
    #pragma unroll
    for (int r = 0; r < 4; ++r) {
        const float f0 = wrow[2 * r], f1 = wrow[2 * r + 1];
        const unsigned int h0 = __float_as_uint(f0) & 0xffff0000u;
        const unsigned int h1 = __float_as_uint(f1) & 0xffff0000u;
        const float l0 = f0 - __uint_as_float(h0);
        const float l1 = f1 - __uint_as_float(h1);
        H.u[r] = h1 | (h0 >> 16);
        L.u[r] = (__float_as_uint(l1) & 0xffff0000u) | (__float_as_uint(l0) >> 16);
    }
    *hi = H.v; *lo = L.v;
}

__device__ __forceinline__ void unpack_a(const unsigned int* __restrict__ Tu,
                                         bf16x8* hi, bf16x8* lo) {
    union { unsigned int u[4]; bf16x8 v; } H, L;
    #pragma unroll
    for (int r = 0; r < 4; ++r) {
        const unsigned int a = Tu[2 * r + 1], bb = Tu[2 * r];
        H.u[r] = __builtin_amdgcn_perm(a, bb, 0x07060302u);  // [a.hi16 : b.hi16]
        L.u[r] = __builtin_amdgcn_perm(a, bb, 0x05040100u);  // [a.lo16 : b.lo16]
    }
    *hi = H.v; *lo = L.v;
}

__device__ __forceinline__ f32x4 mfma3(f32x4 acc, bf16x8 ah, bf16x8 al,
                                       bf16x8 bh, bf16x8 bl) {
    acc = __builtin_amdgcn_mfma_f32_16x16x32_bf16(ah, bl, acc, 0, 0, 0);
    acc = __builtin_amdgcn_mfma_f32_16x16x32_bf16(al, bh, acc, 0, 0, 0);
    acc = __builtin_amdgcn_mfma_f32_16x16x32_bf16(ah, bh, acc, 0, 0, 0);
    return acc;
}

__global__ __launch_bounds__(256, 4) void feat_kernel(
    const float* __restrict__ pc1, const float* __restrict__ pc2,
    const float* __restrict__ feat1, const float* __restrict__ feat2,
    const float* __restrict__ pos_w, const float* __restrict__ pos_b,
    const float* __restrict__ w0, const float* __restrict__ b0,
    const float* __restrict__ w1, const float* __restrict__ b1,
    const float* __restrict__ t1w, const float* __restrict__ t1b,
    const float* __restrict__ t2w, const float* __restrict__ t2b,
    const int* __restrict__ knn, float* __restrict__ out)
{
    __shared__ unsigned int T0[FP][16][68];   // 17.4 KB packed activations
    __shared__ unsigned int T1[FP][16][68];   // 17.4 KB
    __shared__ float sm[FP][64];              // 1 KB pooled features

    const int t    = threadIdx.x;
    const int w    = t >> 6;          // wave = N-tile index 0..3
    const int lane = t & 63;
    const int m    = lane & 15;       // A-row (neighbor) / C-col (channel)
    const int quad = lane >> 4;

    const int p0  = blockIdx.x * FP;
    const int dir = p0 >> 14, bt = (p0 >> 13) & 1;
    const int n0  = p0 & (NPTS - 1);

    const float* __restrict__ pqd = dir ? pc2 : pc1;
    const float* __restrict__ pcd = dir ? pc1 : pc2;
    const float* __restrict__ fqd = dir ? feat2 : feat1;
    const float* __restrict__ fcd = dir ? feat1 : feat2;

    // ---- register-resident B-fragments: B[k][n] = W[n_glob][k] -------------
    const int ocol = w * 16 + m;               // this lane's output channel
    bf16x8 Bh[2][2], Bl[2][2];                 // [layer][ktile]
    #pragma unroll
    for (int kt = 0; kt < 2; ++kt) {
        build_b(&w0[(size_t)ocol * 64 + kt * 32 + quad * 8], &Bh[0][kt], &Bl[0][kt]);
        build_b(&w1[(size_t)ocol * 64 + kt * 32 + quad * 8], &Bh[1][kt], &Bl[1][kt]);
    }
    const float bias1 = b0[ocol];
    const float bias2 = b1[ocol];

    // ---- init-stage per-lane constants: channels cg0..cg0+3 ----------------
    const int cg0 = w * 16 + quad * 4;
    float pbc[4], pwx[4], pwy[4], pwz[4];
    #pragma unroll
    for (int i = 0; i < 4; ++i) {
        pbc[i] = pos_b[cg0 + i];
        pwx[i] = pos_w[(cg0 + i) * 3 + 0];
        pwy[i] = pos_w[(cg0 + i) * 3 + 1];
        pwz[i] = pos_w[(cg0 + i) * 3 + 2];
    }

    // ---- stage A: initial layer -> T0 (packed) -----------------------------
    #pragma unroll
    for (int pt = 0; pt < FP; ++pt) {
        const int p = p0 + pt, n = n0 + pt;
        const int id = knn[(size_t)p * KNNK + m];
        const float* qp  = pqd + ((size_t)bt * NPTS + n) * 3;
        const float* nbp = pcd + ((size_t)bt * NPTS + id) * 3;
        const float dx = nbp[0] - qp[0];
        const float dy = nbp[1] - qp[1];
        const float dz = nbp[2] - qp[2];
        const float4 gf = *(const float4*)&fcd[((size_t)bt * NPTS + id) * 64 + cg0];
        const float4 fq = *(const float4*)&fqd[((size_t)bt * NPTS + n) * 64 + cg0];
        const float gfa[4] = {gf.x, gf.y, gf.z, gf.w};
        const float fqa[4] = {fq.x, fq.y, fq.z, fq.w};
        uint4 U;
        unsigned int* Up = (unsigned int*)&U;
        #pragma unroll
        for (int i = 0; i < 4; ++i) {
            float v = gfa[i] + fqa[i] + pbc[i];
            v = fmaf(dx, pwx[i], v);
            v = fmaf(dy, pwy[i], v);
            v = fmaf(dz, pwz[i], v);
            v = fmaxf(v, LEAKY * v);
            Up[i] = packhl(v);
        }
        *(uint4*)&T0[pt][m][cg0] = U;
    }
    __syncthreads();

    // ---- stage B: layer 1 (MFMA) -> T1 -------------------------------------
    #pragma unroll
    for (int pt = 0; pt < FP; ++pt) {
        unsigned int Tu[8];
        bf16x8 Ah, Al;
        f32x4 acc = {0.f, 0.f, 0.f, 0.f};
        #pragma unroll
        for (int kt = 0; kt < 2; ++kt) {
            *(uint4*)&Tu[0] = *(const uint4*)&T0[pt][m][kt * 32 + quad * 8];
            *(uint4*)&Tu[4] = *(const uint4*)&T0[pt][m][kt * 32 + quad * 8 + 4];
            unpack_a(Tu, &Ah, &Al);
            acc = mfma3(acc, Ah, Al, Bh[0][kt], Bl[0][kt]);
        }
        #pragma unroll
        for (int r = 0; r < 4; ++r) {
            float v = acc[r] + bias1;
            v = fmaxf(v, LEAKY * v);
            T1[pt][quad * 4 + r][ocol] = packhl(v);
        }
    }
    __syncthreads();

    // ---- stage C: layer 2 (MFMA) + max-pool -> sm --------------------------
    #pragma unroll
    for (int pt = 0; pt < FP; ++pt) {
        unsigned int Tu[8];
        bf16x8 Ah, Al;
        f32x4 acc = {0.f, 0.f, 0.f, 0.f};
        #pragma unroll
        for (int kt = 0; kt < 2; ++kt) {
            *(uint4*)&Tu[0] = *(const uint4*)&T1[pt][m][kt * 32 + quad * 8];
            *(uint4*)&Tu[4] = *(const uint4*)&T1[pt][m][kt * 32 + quad * 8 + 4];
            unpack_a(Tu, &Ah, &Al);
            acc = mfma3(acc, Ah, Al, Bh[1][kt], Bl[1][kt]);
        }
        float mx = -3.0e38f;
        #pragma unroll
        for (int r = 0; r < 4; ++r) {
            float v = acc[r] + bias2;
            v = fmaxf(v, LEAKY * v);
            mx = fmaxf(mx, v);
        }
        mx = fmaxf(mx, __shfl_xor(mx, 16));
        mx = fmaxf(mx, __shfl_xor(mx, 32));
        if (quad == 0) sm[pt][ocol] = mx;
    }
    __syncthreads();

    // ---- stage D: final 64->128 linear -------------------------------------
    {
        const float* __restrict__ tw = dir ? t2w : t1w;
        const float* __restrict__ tb = dir ? t2b : t1b;
        const int o  = t & 127;
        const int pg = t >> 7;                 // 2 point-pairs
        const int pa = pg * 2, pb = pg * 2 + 1;
        float acc0 = tb[o], acc1 = acc0;
        #pragma unroll
        for (int cc = 0; cc < 64; cc += 4) {
            const float4 wq = *(const float4*)&tw[(size_t)o * 64 + cc];
            const float4 a0 = *(const float4*)&sm[pa][cc];
            const float4 a1 = *(const float4*)&sm[pb][cc];
            acc0 = fmaf(a0.x, wq.x, acc0); acc0 = fmaf(a0.y, wq.y, acc0);
            acc0 = fmaf(a0.z, wq.z, acc0); acc0 = fmaf(a0.w, wq.w, acc0);
            acc1 = fmaf(a1.x, wq.x, acc1); acc1 = fmaf(a1.y, wq.y, acc1);
            acc1 = fmaf(a1.z, wq.z, acc1); acc1 = fmaf(a1.w, wq.w, acc1);
        }
        float* op = out + (size_t)dir * (2 * NPTS * 128);
        op[((size_t)bt * NPTS + n0 + pa) * 128 + o] = acc0;
        op[((size_t)bt * NPTS + n0 + pb) * 128 + o] = acc1;
    }
}

// ---------------------------------------------------------------------------
extern "C" void kernel_launch(void* const* d_in, const int* in_sizes, int n_in,
                              void* d_out, int out_size, void* d_ws, size_t ws_size,
                              hipStream_t stream)
{
    const float* pc1   = (const float*)d_in[0];
    const float* pc2   = (const float*)d_in[1];
    const float* feat1 = (const float*)d_in[2];
    const float* feat2 = (const float*)d_in[3];
    const float* pos_w = (const float*)d_in[4];
    const float* pos_b = (const float*)d_in[5];
    const float* w0    = (const float*)d_in[6];
    const float* b0    = (const float*)d_in[7];
    const float* w1    = (const float*)d_in[8];
    const float* b1    = (const float*)d_in[9];
    const float* t1w   = (const float*)d_in[10];
    const float* t1b   = (const float*)d_in[11];
    const float* t2w   = (const float*)d_in[12];
    const float* t2b   = (const float*)d_in[13];

    int*   knn = (int*)d_ws;          // 32768 * 16 ints = 2 MB scratch
    float* out = (float*)d_out;

    hipLaunchKernelGGL(knn_kernel, dim3(32768 / QPB), dim3(KTH), 0, stream,
                       pc1, pc2, knn);
    hipLaunchKernelGGL(feat_kernel, dim3(32768 / FP), dim3(256), 0, stream,
                       pc1, pc2, feat1, feat2, pos_w, pos_b,
                       w0, b0, w1, b1, t1w, t1b, t2w, t2b, knn, out);
}